// Round 4
// baseline (463.202 us; speedup 1.0000x reference)
//
#include <hip/hip_runtime.h>

#define NUM_CELLS 8192
#define COLS 1024

typedef float vf4 __attribute__((ext_vector_type(4)));
// 4-byte-aligned float4 view for the shifted (j = 4m-1) W read windows
typedef vf4 uvf4 __attribute__((aligned(4)));

// Pass 1: new_active (out[0..8191]), anomaly (out[16384]), learn-gate flag (ws[0])
__global__ __launch_bounds__(1024) void prep_kernel(
    const float* __restrict__ act_cols, const float* __restrict__ pred,
    const float* __restrict__ prev, float* __restrict__ out,
    float* __restrict__ ws) {
  const int t = threadIdx.x;  // one thread per column, 1024 threads
  const vf4* __restrict__ pred4 = (const vf4*)pred;
  const vf4* __restrict__ prev4 = (const vf4*)prev;

  const vf4 p0 = pred4[t * 2 + 0];
  const vf4 p1 = pred4[t * 2 + 1];
  const vf4 q0 = prev4[t * 2 + 0];
  const vf4 q1 = prev4[t * 2 + 1];

  const float colsum = p0.x + p0.y + p0.z + p0.w + p1.x + p1.y + p1.z + p1.w;
  const bool has_pred = colsum > 0.f;
  const bool active = act_cols[t] > 0.f;

  vf4 o0, o1;
  if (active) {
    if (has_pred) { o0 = p0; o1 = p1; }
    else          { o0 = (vf4){1.f,1.f,1.f,1.f}; o1 = (vf4){1.f,1.f,1.f,1.f}; }
  } else {
    o0 = (vf4){0.f,0.f,0.f,0.f}; o1 = o0;
  }
  ((vf4*)out)[t * 2 + 0] = o0;
  ((vf4*)out)[t * 2 + 1] = o1;

  float nA = active ? 1.f : 0.f;
  float nP = (active && has_pred) ? 1.f : 0.f;
  float ps = q0.x + q0.y + q0.z + q0.w + q1.x + q1.y + q1.z + q1.w;

#pragma unroll
  for (int off = 32; off; off >>= 1) {
    nA += __shfl_down(nA, off);
    nP += __shfl_down(nP, off);
    ps += __shfl_down(ps, off);
  }
  __shared__ float sA[16], sP[16], sS[16];
  const int wid = t >> 6;
  if ((t & 63) == 0) { sA[wid] = nA; sP[wid] = nP; sS[wid] = ps; }
  __syncthreads();
  if (t == 0) {
    float a = 0.f, pp = 0.f, s = 0.f;
    for (int i = 0; i < 16; i++) { a += sA[i]; pp += sP[i]; s += sS[i]; }
    out[2 * NUM_CELLS] = 1.0f - pp / fmaxf(a, 1.0f);  // anomaly
    ws[0] = (s > 0.f) ? 1.f : 0.f;                    // learn gate
  }
}

__device__ __forceinline__ float upd1(float w, float a, bool learn) {
  return learn ? fminf(fmaxf(w + ((a > 0.5f) ? 0.1f : -0.01f), 0.f), 1.f) : w;
}

// Pass 2: fused (connected @ new_active) row-reduction + permanence update.
// One WAVE per row (4 rows / 256-thread block); no LDS, no barriers, no shuffles
// in the hot loop. W' starts at out elem 16385 (4B-aligned region), so slot m
// (m = k*64+lane, m>=1) processes the SHIFTED window j = [4m-1 .. 4m+2]:
//   - W read at Wrow + 4m-1: 4B-aligned dwordx4 (single instr on gfx950)
//   - W' store at out + 16384 + row*8192 + 4m: perfectly 16B-aligned dwordx4
// Slot (k=0, lane=0) handles the edges j = 0,1,2,8191 with scalar ops.
//
// W' main store is NONTEMPORAL (evict-first): W' is write-once, 268 MB.
// Default allocation of the write stream churns L3 and evicts W lines
// (round-2 counters: FETCH_SIZE = 132 MB = exactly half of W retained).
// Evict-first W' lines should preferentially evict THEMSELVES, raising W's
// L3 retention across iterations. W loads stay default-cached (round 1
// showed nt-loads on W destroy that retention). Stores here are full
// wave-contiguous 1KB per instruction, so whole 64B lines complete before
// early eviction (unlike round 1's split dword stores).
__global__ __launch_bounds__(256) void fused_kernel(
    const float* __restrict__ W, const float* __restrict__ prev,
    float* __restrict__ out, const float* __restrict__ ws) {
  const int lane = threadIdx.x & 63;
  const int row = (blockIdx.x << 2) | (threadIdx.x >> 6);  // 2048 blocks x 4 waves

  const bool learn = (prev[row] * ws[0]) > 0.f;  // wave-uniform
  const float* __restrict__ Wrow = W + (size_t)row * NUM_CELLS;
  const float* __restrict__ A = out;  // new_active at out[0..8191]
  float* __restrict__ Orow = out + 2 * NUM_CELLS + 1 + (size_t)row * NUM_CELLS;

  float sum = 0.f;

  // ---- peeled k = 0: lane 0 does the 4 edge elements, lanes 1..63 window m=lane
  if (lane == 0) {
    const vf4 w = *(const vf4*)Wrow;   // elements 0..3 (16B-aligned)
    const vf4 a = *(const vf4*)A;
    sum += ((w.x >= 0.5f) ? a.x : 0.f) + ((w.y >= 0.5f) ? a.y : 0.f) +
           ((w.z >= 0.5f) ? a.z : 0.f);
    Orow[0] = upd1(w.x, a.x, learn);
    Orow[1] = upd1(w.y, a.y, learn);
    Orow[2] = upd1(w.z, a.z, learn);
    const float wl = Wrow[NUM_CELLS - 1];
    const float al = A[NUM_CELLS - 1];
    sum += (wl >= 0.5f) ? al : 0.f;
    Orow[NUM_CELLS - 1] = upd1(wl, al, learn);
  } else {
    const int j = 4 * lane - 1;
    const uvf4 w = *(const uvf4*)(Wrow + j);
    const uvf4 a = *(const uvf4*)(A + j);
    sum += ((w.x >= 0.5f) ? a.x : 0.f) + ((w.y >= 0.5f) ? a.y : 0.f) +
           ((w.z >= 0.5f) ? a.z : 0.f) + ((w.w >= 0.5f) ? a.w : 0.f);
    vf4 u;
    u.x = upd1(w.x, a.x, learn);
    u.y = upd1(w.y, a.y, learn);
    u.z = upd1(w.z, a.z, learn);
    u.w = upd1(w.w, a.w, learn);
    __builtin_nontemporal_store(u, (vf4*)(Orow + j));  // 16B-aligned
  }

  // ---- main loop: branch-free, independent slots ----
#pragma unroll 4
  for (int k = 1; k < 32; k++) {
    const int j = 4 * ((k << 6) | lane) - 1;
    const uvf4 w = *(const uvf4*)(Wrow + j);
    const uvf4 a = *(const uvf4*)(A + j);
    sum += ((w.x >= 0.5f) ? a.x : 0.f) + ((w.y >= 0.5f) ? a.y : 0.f) +
           ((w.z >= 0.5f) ? a.z : 0.f) + ((w.w >= 0.5f) ? a.w : 0.f);
    vf4 u;
    u.x = upd1(w.x, a.x, learn);
    u.y = upd1(w.y, a.y, learn);
    u.z = upd1(w.z, a.z, learn);
    u.w = upd1(w.w, a.w, learn);
    __builtin_nontemporal_store(u, (vf4*)(Orow + j));  // 16B-aligned
  }

  // wave-local reduction, result in lane 0 — no LDS, no barrier
#pragma unroll
  for (int off = 32; off; off >>= 1) sum += __shfl_down(sum, off);
  if (lane == 0)
    out[NUM_CELLS + row] = (sum >= 13.0f) ? 1.f : 0.f;  // new_predictive
}

extern "C" void kernel_launch(void* const* d_in, const int* in_sizes, int n_in,
                              void* d_out, int out_size, void* d_ws, size_t ws_size,
                              hipStream_t stream) {
  const float* act_cols = (const float*)d_in[0];  // [1024]
  const float* W = (const float*)d_in[1];         // [8192*8192]
  const float* pred = (const float*)d_in[2];      // [8192]
  const float* prev = (const float*)d_in[3];      // [8192]
  float* out = (float*)d_out;
  float* ws = (float*)d_ws;

  prep_kernel<<<1, 1024, 0, stream>>>(act_cols, pred, prev, out, ws);
  fused_kernel<<<NUM_CELLS / 4, 256, 0, stream>>>(W, prev, out, ws);
}

// Round 5
// 450.423 us; speedup vs baseline: 1.0284x; 1.0284x over previous
//
#include <hip/hip_runtime.h>

#define NUM_CELLS 8192
#define COLS 1024

typedef float vf4 __attribute__((ext_vector_type(4)));
// 4-byte-aligned float4 view for the shifted (j = 4m-1) W read windows
typedef vf4 uvf4 __attribute__((aligned(4)));

// Pass 1: new_active (out[0..8191]), anomaly (out[16384]).
// NOTE: no workspace use anywhere — the learn gate prev[row]*(sum(prev)>0)
// is equivalent to prev[row]>0 (prev[row]>0 implies the global gate), and
// rows with prev[row]==0 are exact pass-through in the reference anyway
// (clip(W+0-0)=W for W in [0,1)). Avoiding d_ws avoids its 1 GiB re-poison
// fill in the timed loop.
__global__ __launch_bounds__(1024) void prep_kernel(
    const float* __restrict__ act_cols, const float* __restrict__ pred,
    float* __restrict__ out) {
  const int t = threadIdx.x;  // one thread per column, 1024 threads
  const vf4* __restrict__ pred4 = (const vf4*)pred;

  const vf4 p0 = pred4[t * 2 + 0];
  const vf4 p1 = pred4[t * 2 + 1];

  const float colsum = p0.x + p0.y + p0.z + p0.w + p1.x + p1.y + p1.z + p1.w;
  const bool has_pred = colsum > 0.f;
  const bool active = act_cols[t] > 0.f;

  vf4 o0, o1;
  if (active) {
    if (has_pred) { o0 = p0; o1 = p1; }
    else          { o0 = (vf4){1.f,1.f,1.f,1.f}; o1 = (vf4){1.f,1.f,1.f,1.f}; }
  } else {
    o0 = (vf4){0.f,0.f,0.f,0.f}; o1 = o0;
  }
  ((vf4*)out)[t * 2 + 0] = o0;
  ((vf4*)out)[t * 2 + 1] = o1;

  float nA = active ? 1.f : 0.f;
  float nP = (active && has_pred) ? 1.f : 0.f;

#pragma unroll
  for (int off = 32; off; off >>= 1) {
    nA += __shfl_down(nA, off);
    nP += __shfl_down(nP, off);
  }
  __shared__ float sA[16], sP[16];
  const int wid = t >> 6;
  if ((t & 63) == 0) { sA[wid] = nA; sP[wid] = nP; }
  __syncthreads();
  if (t == 0) {
    float a = 0.f, pp = 0.f;
    for (int i = 0; i < 16; i++) { a += sA[i]; pp += sP[i]; }
    out[2 * NUM_CELLS] = 1.0f - pp / fmaxf(a, 1.0f);  // anomaly
  }
}

__device__ __forceinline__ float upd1(float w, float a, bool learn) {
  return learn ? fminf(fmaxf(w + ((a > 0.5f) ? 0.1f : -0.01f), 0.f), 1.f) : w;
}

// Pass 2: fused (connected @ new_active) row-reduction + permanence update.
// One WAVE per row (4 rows / 256-thread block); no LDS/barriers/shuffles in
// the hot loop. W' starts at out elem 16385 (4B-aligned region): slot m
// (m = k*64+lane, m>=1) processes the SHIFTED window j = [4m-1 .. 4m+2]:
//   - W read at Wrow + 4m-1: 4B-aligned dwordx4
//   - W' store at out + 16384 + row*8192 + 4m: 16B-aligned dwordx4,
//     wave-contiguous 1KB covering whole 64B lines
// Slot (k=0, lane=0) handles edges j = 0,1,2,8191 scalar.
//
// Main loop is an EXPLICIT 2-stage register pipeline: round-4 counters showed
// VGPR_Count=24, i.e. the compiler kept one load in flight and serialized each
// iteration on memory latency. Loading k+1 before computing/storing k forces
// the next loads to issue under the current waitcnt shadow.
__global__ __launch_bounds__(256) void fused_kernel(
    const float* __restrict__ W, const float* __restrict__ prev,
    float* __restrict__ out) {
  const int lane = threadIdx.x & 63;
  const int row = (blockIdx.x << 2) | (threadIdx.x >> 6);  // 2048 blocks x 4 waves

  const bool learn = prev[row] > 0.f;  // wave-uniform; no global gate needed
  const float* __restrict__ Wrow = W + (size_t)row * NUM_CELLS;
  const float* __restrict__ A = out;  // new_active at out[0..8191]
  float* __restrict__ Orow = out + 2 * NUM_CELLS + 1 + (size_t)row * NUM_CELLS;

  float sum = 0.f;

  // ---- peeled k = 0: lane 0 does the 4 edge elements, lanes 1..63 window m=lane
  if (lane == 0) {
    const vf4 w = *(const vf4*)Wrow;   // elements 0..3 (16B-aligned)
    const vf4 a = *(const vf4*)A;
    sum += ((w.x >= 0.5f) ? a.x : 0.f) + ((w.y >= 0.5f) ? a.y : 0.f) +
           ((w.z >= 0.5f) ? a.z : 0.f);
    Orow[0] = upd1(w.x, a.x, learn);
    Orow[1] = upd1(w.y, a.y, learn);
    Orow[2] = upd1(w.z, a.z, learn);
    const float wl = Wrow[NUM_CELLS - 1];
    const float al = A[NUM_CELLS - 1];
    sum += (wl >= 0.5f) ? al : 0.f;
    Orow[NUM_CELLS - 1] = upd1(wl, al, learn);
  } else {
    const int j = 4 * lane - 1;
    const uvf4 w = *(const uvf4*)(Wrow + j);
    const uvf4 a = *(const uvf4*)(A + j);
    sum += ((w.x >= 0.5f) ? a.x : 0.f) + ((w.y >= 0.5f) ? a.y : 0.f) +
           ((w.z >= 0.5f) ? a.z : 0.f) + ((w.w >= 0.5f) ? a.w : 0.f);
    vf4 u;
    u.x = upd1(w.x, a.x, learn);
    u.y = upd1(w.y, a.y, learn);
    u.z = upd1(w.z, a.z, learn);
    u.w = upd1(w.w, a.w, learn);
    *(vf4*)(Orow + j) = u;  // 16B-aligned
  }

  // ---- main loop, software-pipelined 2-deep ----
  int j = 4 * (64 | lane) - 1;                 // k = 1
  uvf4 w = *(const uvf4*)(Wrow + j);
  uvf4 a = *(const uvf4*)(A + j);
  for (int k = 1; k < 31; k++) {
    const int jn = 4 * (((k + 1) << 6) | lane) - 1;
    const uvf4 wn = *(const uvf4*)(Wrow + jn);  // issue next loads first
    const uvf4 an = *(const uvf4*)(A + jn);
    sum += ((w.x >= 0.5f) ? a.x : 0.f) + ((w.y >= 0.5f) ? a.y : 0.f) +
           ((w.z >= 0.5f) ? a.z : 0.f) + ((w.w >= 0.5f) ? a.w : 0.f);
    vf4 u;
    u.x = upd1(w.x, a.x, learn);
    u.y = upd1(w.y, a.y, learn);
    u.z = upd1(w.z, a.z, learn);
    u.w = upd1(w.w, a.w, learn);
    *(vf4*)(Orow + j) = u;  // 16B-aligned
    w = wn; a = an; j = jn;
  }
  {  // epilogue: k = 31
    sum += ((w.x >= 0.5f) ? a.x : 0.f) + ((w.y >= 0.5f) ? a.y : 0.f) +
           ((w.z >= 0.5f) ? a.z : 0.f) + ((w.w >= 0.5f) ? a.w : 0.f);
    vf4 u;
    u.x = upd1(w.x, a.x, learn);
    u.y = upd1(w.y, a.y, learn);
    u.z = upd1(w.z, a.z, learn);
    u.w = upd1(w.w, a.w, learn);
    *(vf4*)(Orow + j) = u;
  }

  // wave-local reduction, result in lane 0 — no LDS, no barrier
#pragma unroll
  for (int off = 32; off; off >>= 1) sum += __shfl_down(sum, off);
  if (lane == 0)
    out[NUM_CELLS + row] = (sum >= 13.0f) ? 1.f : 0.f;  // new_predictive
}

extern "C" void kernel_launch(void* const* d_in, const int* in_sizes, int n_in,
                              void* d_out, int out_size, void* d_ws, size_t ws_size,
                              hipStream_t stream) {
  const float* act_cols = (const float*)d_in[0];  // [1024]
  const float* W = (const float*)d_in[1];         // [8192*8192]
  const float* pred = (const float*)d_in[2];      // [8192]
  const float* prev = (const float*)d_in[3];      // [8192]
  float* out = (float*)d_out;
  (void)d_ws; (void)ws_size;  // workspace intentionally unused

  prep_kernel<<<1, 1024, 0, stream>>>(act_cols, pred, out);
  fused_kernel<<<NUM_CELLS / 4, 256, 0, stream>>>(W, prev, out);
}

// Round 6
// 439.845 us; speedup vs baseline: 1.0531x; 1.0240x over previous
//
#include <hip/hip_runtime.h>

#define NUM_CELLS 8192
#define COLS 1024

typedef float vf4 __attribute__((ext_vector_type(4)));
// 4-byte-aligned float4 view for the shifted (j = 4m-1) read windows
typedef vf4 uvf4 __attribute__((aligned(4)));

// Pass 1: new_active (out[0..8191]), anomaly (out[16384]).
// Learn gate is per-row (prev[row] > 0): prev[row]>0 implies the reference's
// global gate sum(prev)>0, and rows with prev[row]==0 are exact pass-through
// (clip(W+0-0)=W for W in [0,1)). No workspace needed.
__global__ __launch_bounds__(1024) void prep_kernel(
    const float* __restrict__ act_cols, const float* __restrict__ pred,
    float* __restrict__ out) {
  const int t = threadIdx.x;  // one thread per column, 1024 threads
  const vf4* __restrict__ pred4 = (const vf4*)pred;

  const vf4 p0 = pred4[t * 2 + 0];
  const vf4 p1 = pred4[t * 2 + 1];

  const float colsum = p0.x + p0.y + p0.z + p0.w + p1.x + p1.y + p1.z + p1.w;
  const bool has_pred = colsum > 0.f;
  const bool active = act_cols[t] > 0.f;

  vf4 o0, o1;
  if (active) {
    if (has_pred) { o0 = p0; o1 = p1; }
    else          { o0 = (vf4){1.f,1.f,1.f,1.f}; o1 = (vf4){1.f,1.f,1.f,1.f}; }
  } else {
    o0 = (vf4){0.f,0.f,0.f,0.f}; o1 = o0;
  }
  ((vf4*)out)[t * 2 + 0] = o0;
  ((vf4*)out)[t * 2 + 1] = o1;

  float nA = active ? 1.f : 0.f;
  float nP = (active && has_pred) ? 1.f : 0.f;

#pragma unroll
  for (int off = 32; off; off >>= 1) {
    nA += __shfl_down(nA, off);
    nP += __shfl_down(nP, off);
  }
  __shared__ float sA[16], sP[16];
  const int wid = t >> 6;
  if ((t & 63) == 0) { sA[wid] = nA; sP[wid] = nP; }
  __syncthreads();
  if (t == 0) {
    float a = 0.f, pp = 0.f;
    for (int i = 0; i < 16; i++) { a += sA[i]; pp += sP[i]; }
    out[2 * NUM_CELLS] = 1.0f - pp / fmaxf(a, 1.0f);  // anomaly
  }
}

__device__ __forceinline__ float upd1(float w, float a, bool learn) {
  return learn ? fminf(fmaxf(w + ((a > 0.5f) ? 0.1f : -0.01f), 0.f), 1.f) : w;
}

// Pass 2: fused (connected @ new_active) row-reduction + permanence update.
// BLOCK-per-row (8192 blocks x 256 threads) — the empirically fastest mapping
// (round 0: best session total), now with ALIGNED stores via shifted windows:
// thread slot m = k*256 + t (m>=1) processes j = [4m-1 .. 4m+2]:
//   - W/A reads at +4m-1: 4B-aligned dwordx4 (single instr)
//   - W' store at out + 16384 + row*8192 + 4m: 16B-aligned dwordx4
// -> 2048 dwordx4 + 4 scalar stores per row instead of round 0's 8192 dwords.
// Slot (k=0, t=0) handles edges j = 0,1,2,8191. No nt hints (r1/r4 both
// regressed), no explicit pipeline (r5 null at 8 waves/SIMD).
__global__ __launch_bounds__(256) void fused_kernel(
    const float* __restrict__ W, const float* __restrict__ prev,
    float* __restrict__ out) {
  const int t = threadIdx.x;
  const int row = blockIdx.x;

  const bool learn = prev[row] > 0.f;  // block-uniform
  const float* __restrict__ Wrow = W + (size_t)row * NUM_CELLS;
  const float* __restrict__ A = out;  // new_active at out[0..8191]
  float* __restrict__ Orow = out + 2 * NUM_CELLS + 1 + (size_t)row * NUM_CELLS;

  float sum = 0.f;

  // ---- peeled k = 0: thread 0 does the 4 edge elements, t>=1 window m=t ----
  if (t == 0) {
    const vf4 w = *(const vf4*)Wrow;  // elements 0..3 (16B-aligned)
    const vf4 a = *(const vf4*)A;
    sum += ((w.x >= 0.5f) ? a.x : 0.f) + ((w.y >= 0.5f) ? a.y : 0.f) +
           ((w.z >= 0.5f) ? a.z : 0.f);
    Orow[0] = upd1(w.x, a.x, learn);
    Orow[1] = upd1(w.y, a.y, learn);
    Orow[2] = upd1(w.z, a.z, learn);
    const float wl = Wrow[NUM_CELLS - 1];
    const float al = A[NUM_CELLS - 1];
    sum += (wl >= 0.5f) ? al : 0.f;
    Orow[NUM_CELLS - 1] = upd1(wl, al, learn);
  } else {
    const int j = 4 * t - 1;
    const uvf4 w = *(const uvf4*)(Wrow + j);
    const uvf4 a = *(const uvf4*)(A + j);
    sum += ((w.x >= 0.5f) ? a.x : 0.f) + ((w.y >= 0.5f) ? a.y : 0.f) +
           ((w.z >= 0.5f) ? a.z : 0.f) + ((w.w >= 0.5f) ? a.w : 0.f);
    vf4 u;
    u.x = upd1(w.x, a.x, learn);
    u.y = upd1(w.y, a.y, learn);
    u.z = upd1(w.z, a.z, learn);
    u.w = upd1(w.w, a.w, learn);
    *(vf4*)(Orow + j) = u;  // 16B-aligned
  }

  // ---- main loop: k = 1..7, branch-free ----
#pragma unroll
  for (int k = 1; k < 8; k++) {
    const int j = 4 * (k * 256 + t) - 1;
    const uvf4 w = *(const uvf4*)(Wrow + j);
    const uvf4 a = *(const uvf4*)(A + j);
    sum += ((w.x >= 0.5f) ? a.x : 0.f) + ((w.y >= 0.5f) ? a.y : 0.f) +
           ((w.z >= 0.5f) ? a.z : 0.f) + ((w.w >= 0.5f) ? a.w : 0.f);
    vf4 u;
    u.x = upd1(w.x, a.x, learn);
    u.y = upd1(w.y, a.y, learn);
    u.z = upd1(w.z, a.z, learn);
    u.w = upd1(w.w, a.w, learn);
    *(vf4*)(Orow + j) = u;  // 16B-aligned
  }

  // block reduction: 4 waves
#pragma unroll
  for (int off = 32; off; off >>= 1) sum += __shfl_down(sum, off);
  __shared__ float s[4];
  if ((t & 63) == 0) s[t >> 6] = sum;
  __syncthreads();
  if (t == 0) {
    const float tot = s[0] + s[1] + s[2] + s[3];
    out[NUM_CELLS + row] = (tot >= 13.0f) ? 1.f : 0.f;  // new_predictive
  }
}

extern "C" void kernel_launch(void* const* d_in, const int* in_sizes, int n_in,
                              void* d_out, int out_size, void* d_ws, size_t ws_size,
                              hipStream_t stream) {
  const float* act_cols = (const float*)d_in[0];  // [1024]
  const float* W = (const float*)d_in[1];         // [8192*8192]
  const float* pred = (const float*)d_in[2];      // [8192]
  const float* prev = (const float*)d_in[3];      // [8192]
  float* out = (float*)d_out;
  (void)d_ws; (void)ws_size;  // workspace unused (its poison is unconditional)

  prep_kernel<<<1, 1024, 0, stream>>>(act_cols, pred, out);
  fused_kernel<<<NUM_CELLS, 256, 0, stream>>>(W, prev, out);
}